// Round 1
// 212.708 us; speedup vs baseline: 1.0374x; 1.0374x over previous
//
#include <hip/hip_runtime.h>
#include <stdint.h>

#define NSEG 50
#define HID 128
#define KDIM 2144      // 64 + 2016 + 64 (original logical K)
#define KD2 2240       // 64 + 2112 (levy padded to 4-pair groups/row) + 64; 35*64
#define KD2B 4480      // row bytes fp16
#define NROW 20000     // 400 * 50
#define NROW_PAD 20096 // 157 * 128
#define GATES 512
#define NSEQ 400
#define NGRP 528       // sum over rows i of ceil((63-i)/4)

typedef __attribute__((ext_vector_type(8))) _Float16 f16x8;
typedef __attribute__((ext_vector_type(4))) _Float16 f16x4;
typedef __attribute__((ext_vector_type(4))) float f32x4;
typedef __attribute__((ext_vector_type(4))) uint32_t u32x4;

#define GLB_SPACE __attribute__((address_space(1)))
#define LDS_SPACE __attribute__((address_space(3)))

__device__ __forceinline__ void g2lds16(const void* g, void* l) {
    __builtin_amdgcn_global_load_lds((const GLB_SPACE uint32_t*)g,
                                     (LDS_SPACE uint32_t*)l, 16, 0, 0);
}

// group-offset of row i in the 4-padded levy layout: goff(i) = 528 - f(63-i),
// f(n) = sum_{L=1..n} ceil(L/4) = (q+1)*(2q+t), n = 4q+t
__device__ __forceinline__ int goff528(int i) {
    int n = 63 - i;
    int q = n >> 2, t = n & 3;
    return NGRP - (q + 1) * (2 * q + t);
}
__device__ __forceinline__ int ifromg(int g) {
    int i = 63 - (int)sqrtf(8.0f * (float)(NGRP - g));
    if (i < 0) i = 0;
    if (i > 62) i = 62;
    while (i > 0 && goff528(i) > g) i--;
    while (goff528(i + 1) <= g) i++;
    return i;
}

// uv4 column permutation: consecutive j with stride 4 -> consecutive banks
#define UVP(c) ((((c) & 3) << 4) | ((c) >> 2))

// ---------------- features (blocks 0..799) + fused weight-prep (blocks 800..863) --------
// dev_0 == 0, so S2 = (p1-p0)x(p2-p1) + (p2-p0)x(p3-p2)
__global__ __launch_bounds__(512) void feat_kernel(const float* __restrict__ x,
                                                   const float* __restrict__ Wih,
                                                   const float* __restrict__ Whh,
                                                   const float* __restrict__ bih,
                                                   const float* __restrict__ bhh,
                                                   _Float16* __restrict__ feat,
                                                   _Float16* __restrict__ wh,
                                                   _Float16* __restrict__ whh16,
                                                   float* __restrict__ bias) {
    int bid = blockIdx.x;
    int tid = threadIdx.x;

    __shared__ float pbuf[64 * 101];                // p[c][t*25+v], stride 101 (bank fix)
    __shared__ __align__(16) float4 uv4[25 * 64];   // (u1,u2,v1,v2) per (v, UVP(c))

    if (bid >= 800) {
        // ---- prep path: permuted-K cast of W_ih to fp16, W_hh cast, bias sum ----
        int* kmap = (int*)pbuf;                     // 2240 ints, aliased onto pbuf
        for (int k = tid; k < KD2; k += 512) {
            int orig;
            if (k < 64) {
                orig = k;                            // lvl1
            } else if (k < 64 + 4 * NGRP) {
                int g = (k - 64) >> 2, p = (k - 64) & 3;
                int i = ifromg(g);
                int j = i + 1 + 4 * (g - goff528(i)) + p;
                orig = (j < 64) ? (64 + 63 * i - (i * (i - 1)) / 2 + (j - i - 1)) : -1;
            } else {
                orig = 2080 + (k - (64 + 4 * NGRP)); // start
            }
            kmap[k] = orig;
        }
        __syncthreads();
        const int nwih = 512 * KD2;
        const int nwhh = 512 * HID;
        const int total = nwih + nwhh + 512;
        for (int idx = (bid - 800) * 512 + tid; idx < total; idx += 64 * 512) {
            if (idx < nwih) {
                int row = idx / KD2;
                int k = idx - row * KD2;
                int orig = kmap[k];
                wh[idx] = (orig >= 0) ? (_Float16)Wih[row * KDIM + orig] : (_Float16)0.0f;
            } else if (idx < nwih + nwhh) {
                int q = idx - nwih;
                whh16[q] = (_Float16)Whh[q];
            } else {
                int g = idx - nwih - nwhh;
                bias[g] = bih[g] + bhh[g];
            }
        }
        return;
    }

    int b = bid / NSEG;
    int s = bid - b * NSEG;

    // load: x[b][c][4s+t][v] -> 100 contiguous floats per c
    for (int i = tid; i < 6400; i += 512) {
        int c = i / 100;
        int r = i - c * 100;
        pbuf[c * 101 + r] = x[(((size_t)b * 64 + c) * 200 + 4 * s) * 25 + r];
    }
    __syncthreads();

    // derived vectors + lvl1/start features
    for (int i = tid; i < 1600; i += 512) {
        int v = i >> 6;
        int c = i & 63;
        float p0 = pbuf[c * 101 + v];
        float p1 = pbuf[c * 101 + 25 + v];
        float p2 = pbuf[c * 101 + 50 + v];
        float p3 = pbuf[c * 101 + 75 + v];
        uv4[v * 64 + UVP(c)] = make_float4(p1 - p0, p2 - p0, p2 - p1, p3 - p2);
        size_t m = ((size_t)(b * 25 + v)) * NSEG + s;
        feat[m * KD2 + c] = (_Float16)(p3 - p0);             // lvl1
        feat[m * KD2 + (64 + 4 * NGRP) + c] = (_Float16)p0;  // start
    }
    __syncthreads();

    // levy: 528 groups of 4 pairs (row-major, row-padded); one 8B store per (group, v)
    for (int g = tid; g < NGRP; g += 512) {
        int i = ifromg(g);
        int t = g - goff528(i);
        int j0 = i + 1 + 4 * t;
        int k0 = 64 + 4 * g;
        float msk[4];
        int jc[4];
#pragma unroll
        for (int p = 0; p < 4; p++) {
            int j = j0 + p;
            msk[p] = (j < 64) ? 0.5f : 0.0f;
            jc[p] = (j < 64) ? UVP(j) : UVP(63);
        }
        int ip = UVP(i);
        for (int v = 0; v < 25; v++) {
            const float4* rowv = &uv4[v * 64];
            float4 a = rowv[ip];
            f16x4 o;
#pragma unroll
            for (int p = 0; p < 4; p++) {
                float4 bb = rowv[jc[p]];
                float val = msk[p] * (a.x * bb.z - bb.x * a.z + a.y * bb.w - bb.y * a.w);
                o[p] = (_Float16)val;
            }
            size_t m = ((size_t)(b * 25 + v)) * NSEG + s;
            *(f16x4*)(feat + m * KD2 + k0) = o;
        }
    }
}

// ---------------- GEMM: xproj2[s][q][gate] = feat @ W_ih^T + bias (fp16 out) ------------
// BM=128, BN=128, BK=64; grid 640, bid&7 XCD-residue mapping.
// NEW: 4 waves/block (256 thr), wave tile 64x64 (af[4] x bf[4], acc[4][4]).
// Rationale: 2-wave blocks measured MfmaUtil 25% / Occupancy 9.4% -> TLP-starved at
// the per-kt barrier drains. 4 blocks/CU (33.8 KB LDS) x 4 waves = 16 waves/CU; the
// whole 640-block grid is co-resident. LDS-BW ceiling drops ~57%->~50% but we were
// nowhere near it.
__global__ __launch_bounds__(256, 4) void gemm_kernel(const _Float16* __restrict__ feat,
                                                      const _Float16* __restrict__ wh,
                                                      const float* __restrict__ bias,
                                                      _Float16* __restrict__ xproj2) {
    int bid = blockIdx.x;
    int x = bid & 7;
    int t = bid >> 3;
    int nb = t & 3;
    int mt = (t >> 2) * 8 + x;
    if (mt >= 157) return;
    int m0 = mt * 128;
    int n0 = nb * 128;
    int tid = threadIdx.x;         // 0..255
    int wave = tid >> 6;           // 0..3
    int lane = tid & 63;
    int quad = lane >> 4;
    int l15 = lane & 15;
    int wm = (wave >> 1) * 64;     // wave M-offset
    int wn = (wave & 1) * 64;      // wave N-offset

    int r8 = lane >> 3;                        // row within 8-row staging group
    int gcol = ((lane & 7) * 16) ^ (r8 * 16);  // XOR-swizzled source byte-col

    __shared__ __align__(16) _Float16 smem[16896];   // 33 KB (K-loop 32 KB; epilogue 128x132)
    char* As = (char*)smem;                    // 128 rows x 128 B
    char* Bs = (char*)smem + 128 * 128;        // 128 rows x 128 B

    const f32x4 z4 = {0.f, 0.f, 0.f, 0.f};
    f32x4 acc[4][4];
    for (int i = 0; i < 4; i++)
        for (int j = 0; j < 4; j++) acc[i][j] = z4;

    const char* featB = (const char*)feat;
    const char* whB = (const char*)wh;

    for (int kt = 0; kt < 35; kt++) {
        size_t kb = (size_t)kt * 128;
        __syncthreads();
        for (int it = 0; it < 4; it++) {       // 128 rows each of A and B, 4 waves
            int rb = it * 32 + wave * 8;
            g2lds16(featB + (size_t)(m0 + rb + r8) * KD2B + kb + gcol, As + rb * 128);
            g2lds16(whB + (size_t)(n0 + rb + r8) * KD2B + kb + gcol, Bs + rb * 128);
        }
        __syncthreads();

        for (int ks = 0; ks < 2; ks++) {
            int off = ((ks * 64) | (quad * 16)) ^ ((l15 & 7) * 16);
            f16x8 af[4], bf[4];
            for (int tt = 0; tt < 4; tt++)
                af[tt] = *(const f16x8*)(As + (wm + tt * 16 + l15) * 128 + off);
            for (int tt = 0; tt < 4; tt++)
                bf[tt] = *(const f16x8*)(Bs + (wn + tt * 16 + l15) * 128 + off);
            for (int mtl = 0; mtl < 4; mtl++)
                for (int ntl = 0; ntl < 4; ntl++)
                    acc[mtl][ntl] = __builtin_amdgcn_mfma_f32_16x16x32_f16(af[mtl], bf[ntl], acc[mtl][ntl], 0, 0, 0);
        }
    }

    // epilogue: stage fp16 tile in LDS (row stride 132 halfwords -> conflict-free writes)
    __syncthreads();
    for (int ntl = 0; ntl < 4; ntl++) {
        int nl = wn + ntl * 16 + l15;
        float bv = bias[n0 + nl];
        for (int mtl = 0; mtl < 4; mtl++)
            for (int r = 0; r < 4; r++) {
                int ml = wm + mtl * 16 + quad * 4 + r;
                smem[ml * 132 + nl] = (_Float16)(acc[mtl][ntl][r] + bv);
            }
    }
    __syncthreads();
    {
        int row = tid >> 1;        // 0..127
        int half = tid & 1;
        int m = m0 + row;
        if (m < NROW) {
            unsigned q = (unsigned)m / 50u;
            unsigned s = (unsigned)m - q * 50u;
            const char* src = (const char*)smem + row * 264 + half * 128;
            char* dst = (char*)xproj2 + ((size_t)s * NSEQ + q) * 1024 + (size_t)n0 * 2 + half * 128;
            for (int i = 0; i < 8; i++)
                *(u32x4*)(dst + i * 16) = *(const u32x4*)(src + i * 16);
        }
    }
}

// ---------------- LSTM: 100 blocks x 4 seqs x 8 waves; NO per-step global ops -----------
// 25 steps of xproj preloaded into LDS (104 KB), refilled once at midpoint; all h
// outputs buffered in LDS (51 KB) and written out coalesced at the end. Steady-state
// step = LDS + MFMA + VALU + barrier only (no vmcnt drain on the critical path).
// Wave w owns hid [w*16,w*16+16) for all 4 gates; A rows replicated h[row&3]; quad=seq.
__global__ __launch_bounds__(512, 2) void lstm_kernel(const _Float16* __restrict__ xproj2,
                                                      const _Float16* __restrict__ whh,
                                                      _Float16* __restrict__ hseq) {
    int bid = blockIdx.x;        // 0..99
    int tid = threadIdx.x;
    int wave = tid >> 6;         // 0..7
    int lane = tid & 63;
    int quad = lane >> 4;        // = this lane's seq
    int col = lane & 15;
    int hid = wave * 16 + col;   // this lane's hid

    __shared__ __align__(16) char xbuf[25 * 4 * 1040];       // 104,000 B, rows padded
    __shared__ __align__(16) _Float16 hst[NSEG * 4 * HID];   // 51,200 B, [s][seq][hid]
    __shared__ __align__(16) _Float16 hbuf[2][4 * 144];      // 2,304 B, stride 144

    // B-frags: bfrag[g][kq]; B[k][n] = whh[g*128 + hid][k]
    f16x8 bfrag[4][4];
    for (int g = 0; g < 4; g++) {
        int n = g * 128 + hid;
        for (int kq = 0; kq < 4; kq++)
            bfrag[g][kq] = *(const f16x8*)(whh + (size_t)n * HID + kq * 32 + quad * 8);
    }
    for (int i = tid; i < 2 * 4 * 144; i += 512) ((_Float16*)hbuf)[i] = (_Float16)0.0f;
    float cst = 0.0f;

    const char* xsrc = (const char*)xproj2;
    // preload steps 0..24 (100 rows of 1 KB), 12-13 g2lds per wave
    for (int r = wave; r < 100; r += 8)
        g2lds16(xsrc + ((size_t)((r >> 2) * NSEQ + bid * 4 + (r & 3))) * 1024 + lane * 16,
                xbuf + r * 1040);
    __syncthreads();

    const f32x4 z4 = {0.f, 0.f, 0.f, 0.f};
    for (int half = 0; half < 2; half++) {
        for (int ss = 0; ss < 25; ss++) {
            int s = half * 25 + ss;
            int cur = s & 1;
            int nxt = cur ^ 1;

            // A-frags: A[m][k] = h[m&3][k] (replicated rows)
            f16x8 afrag[4];
            for (int kq = 0; kq < 4; kq++)
                afrag[kq] = *(const f16x8*)(&hbuf[cur][(col & 3) * 144 + kq * 32 + quad * 8]);

            // x_proj gates from LDS: 4 scalar reads for (seq=quad, hid)
            float xp[4];
            for (int g = 0; g < 4; g++)
                xp[g] = (float)(*(const _Float16*)(xbuf + (ss * 4 + quad) * 1040 +
                               (g * 128 + hid) * 2));

            f32x4 acc[4];
            for (int g = 0; g < 4; g++) {
                acc[g] = z4;
                for (int kq = 0; kq < 4; kq++)
                    acc[g] = __builtin_amdgcn_mfma_f32_16x16x32_f16(afrag[kq], bfrag[g][kq], acc[g], 0, 0, 0);
            }

            // extract element [quad] of each gate vector (C row quad*4+r = seq r)
            float gv[4];
            for (int g = 0; g < 4; g++) {
                float lo = (quad & 1) ? acc[g][1] : acc[g][0];
                float hi = (quad & 1) ? acc[g][3] : acc[g][2];
                gv[g] = (quad & 2) ? hi : lo;
            }

            float ip = gv[0] + xp[0];
            float fp = gv[1] + xp[1];
            float gp = gv[2] + xp[2];
            float op = gv[3] + xp[3];
            float si = __fdividef(1.0f, 1.0f + __expf(-ip));
            float sf = __fdividef(1.0f, 1.0f + __expf(-fp));
            float so = __fdividef(1.0f, 1.0f + __expf(-op));
            float eg = __expf(-2.0f * gp);
            float tg = __fdividef(1.0f - eg, 1.0f + eg);
            cst = sf * cst + si * tg;
            float ec = __expf(-2.0f * cst);
            float tc = __fdividef(1.0f - ec, 1.0f + ec);
            float hv = so * tc;
            _Float16 hv16 = (_Float16)hv;
            hbuf[nxt][quad * 144 + hid] = hv16;
            hst[(s * 4 + quad) * 128 + hid] = hv16;
            __syncthreads();
        }
        if (half == 0) {
            // refill slots 0..24 with steps 25..49 (one-time vmcnt drain)
            for (int r = wave; r < 100; r += 8)
                g2lds16(xsrc + ((size_t)((25 + (r >> 2)) * NSEQ + bid * 4 + (r & 3))) * 1024 + lane * 16,
                        xbuf + r * 1040);
            __syncthreads();
        }
    }

    // coalesced writeout of all 50 steps: 3200 dwordx4
    const u32x4* src = (const u32x4*)hst;
    for (int i = tid; i < 3200; i += 512) {
        int s = i >> 6;            // 64 vec4 per step
        int rem = i & 63;
        int seq = rem >> 4;
        int seg = rem & 15;
        u32x4 v = src[i];
        *(u32x4*)((char*)hseq + ((size_t)(s * NSEQ + bid * 4 + seq)) * 256 + seg * 16) = v;
    }
}

// ---------------- transpose: out[b][hid][s][v] = hseq[s][b*25+v][hid] -------------------
__global__ __launch_bounds__(256) void tr_kernel(const _Float16* __restrict__ hseq,
                                                 float* __restrict__ out) {
    int bid = blockIdx.x;        // 0..799 = b*50+s
    int b = bid / NSEG;
    int s = bid - b * NSEG;
    int tid = threadIdx.x;

    __shared__ _Float16 buf[25 * 130];   // [v][hid], padded 128->130

    const uint32_t* src32 = (const uint32_t*)(hseq + ((size_t)s * NSEQ + b * 25) * HID);
    uint32_t* buf32 = (uint32_t*)buf;
    for (int i = tid; i < 1600; i += 256) {       // 25 rows x 64 dwords, contiguous read
        int v = i >> 6;
        int d = i & 63;
        buf32[v * 65 + d] = src32[i];
    }
    __syncthreads();
    for (int i = tid; i < 3200; i += 256) {
        int hid = i / 25;
        int v = i - hid * 25;
        out[(((size_t)b * 128 + hid) * NSEG + s) * 25 + v] = (float)buf[v * 130 + hid];
    }
}

extern "C" void kernel_launch(void* const* d_in, const int* in_sizes, int n_in,
                              void* d_out, int out_size, void* d_ws, size_t ws_size,
                              hipStream_t stream) {
    const float* x = (const float*)d_in[0];
    const float* Wih = (const float*)d_in[1];
    const float* Whh = (const float*)d_in[2];
    const float* bih = (const float*)d_in[3];
    const float* bhh = (const float*)d_in[4];
    float* out = (float*)d_out;

    char* ws = (char*)d_ws;
    size_t off = 0;
    _Float16* feat = (_Float16*)(ws + off);   off += (size_t)NROW_PAD * KD2 * 2;      // 90.0 MB
    _Float16* xproj2 = (_Float16*)(ws + off); off += (size_t)NSEG * NSEQ * GATES * 2; // 20.5 MB
    _Float16* hseq = (_Float16*)(ws + off);   off += (size_t)NSEG * NSEQ * HID * 2;   // 5.1 MB
    _Float16* wh = (_Float16*)(ws + off);     off += (size_t)512 * KD2 * 2;           // 2.3 MB
    _Float16* whh16 = (_Float16*)(ws + off);  off += (size_t)512 * HID * 2;
    float* bias = (float*)(ws + off);         off += 512 * 4;

    hipLaunchKernelGGL(feat_kernel, dim3(864), dim3(512), 0, stream,
                       x, Wih, Whh, bih, bhh, feat, wh, whh16, bias);
    hipLaunchKernelGGL(gemm_kernel, dim3(640), dim3(256), 0, stream, feat, wh, bias, xproj2);
    hipLaunchKernelGGL(lstm_kernel, dim3(100), dim3(512), 0, stream, xproj2, whh16, hseq);
    hipLaunchKernelGGL(tr_kernel, dim3(16 * NSEG), dim3(256), 0, stream, hseq, out);
}